// Round 13
// baseline (924.335 us; speedup 1.0000x reference)
//
#include <hip/hip_runtime.h>
#include <math.h>

#define BB 2
#define CC 128
#define NN 4096
#define KK 16
#define DIMD 256
#define PHH 64
#define AHH 1024
#define EPSF 1e-5f
#define RSPLIT 128
#define RKCH ((BB * NN * KK) / RSPLIT)   // 1024 samples per R block
#define LSTR 258    // LDS row stride (halfwords): conflict-free transposed gathers
#define KNN_CAP 512
#define FPT 8       // final_kernel points per thread

typedef unsigned short ushort_t;
typedef unsigned char uchar_t;
typedef unsigned long long u64;
typedef long long i64;
typedef __attribute__((ext_vector_type(8))) short short8;
typedef __attribute__((ext_vector_type(8))) unsigned short u16x8;
typedef __attribute__((ext_vector_type(4))) unsigned short u16x4;
typedef __attribute__((ext_vector_type(2))) unsigned short u16x2;
typedef __attribute__((ext_vector_type(4))) float f32x4;

__device__ __forceinline__ ushort_t f2b(float x) {
    union { float f; unsigned u; } v; v.f = x;
    unsigned r = v.u + 0x7fff + ((v.u >> 16) & 1);
    return (ushort_t)(r >> 16);
}
__device__ __forceinline__ float b2f(ushort_t x) {
    union { unsigned u; float f; } v; v.u = ((unsigned)x) << 16;
    return v.f;
}
__device__ __forceinline__ unsigned fsort(float x) {
    union { float f; unsigned u; } v; v.f = x;
    return v.u ^ ((v.u >> 31) ? 0xFFFFFFFFu : 0x80000000u);
}
__device__ __forceinline__ uchar_t f2f8(float x) {
    int p = __builtin_amdgcn_cvt_pk_fp8_f32(x, x, 0, false);
    return (uchar_t)(p & 0xFF);
}

#define GLDS16(gp, lp) __builtin_amdgcn_global_load_lds( \
    (const __attribute__((address_space(1))) void*)(gp), \
    (__attribute__((address_space(3))) void*)(lp), 16, 0, 0)

// ---------------- K0: zero scratch accumulators ----------------
__global__ void zero_kernel(float* p, int n) {
    int i = blockIdx.x * blockDim.x + threadIdx.x;
    if (i < n) p[i] = 0.f;
}

// ---------------- K1: exact kNN via u64-key threshold select ----------------
__global__ __launch_bounds__(256) void knn_kernel(const float* __restrict__ pos,
                                                  int* __restrict__ idx) {
    int bid = blockIdx.x;
    int b = bid / NN, n = bid % NN;
    int t = threadIdx.x;
    int lane = t & 63, w = t >> 6;
    const float* px = pos + (size_t)b * 3 * NN;
    const float* py = px + NN;
    const float* pz = px + 2 * NN;
    float qx = px[n], qy = py[n], qz = pz[n];
    float qs = qx * qx + qy * qy + qz * qz;

    u64 keys[KK];
    u64 lmin = ~0ull;
#pragma unroll
    for (int j = 0; j < KK; ++j) {
        int m = t + 256 * j;
        float mx = px[m], my = py[m], mz = pz[m];
        float ms = mx * mx + my * my + mz * mz;
        float dt = qx * mx + qy * my + qz * mz;
        float d = qs + ms - 2.f * dt;
        u64 k = ((u64)fsort(d) << 32) | (unsigned)m;
        keys[j] = k;
        lmin = k < lmin ? k : lmin;
    }

    __shared__ u64 T0s[4];
    __shared__ u64 pool[KNN_CAP];
    __shared__ int cnt;

    u64 k = lmin, m4 = 0;
#pragma unroll
    for (int r = 0; r < 4; ++r) {
        u64 mv = k;
#pragma unroll
        for (int off = 32; off >= 1; off >>= 1) {
            u64 o = __shfl_xor(mv, off);
            mv = o < mv ? o : mv;
        }
        if (r == 3) m4 = mv;
        if (k == mv) k = ~0ull;
    }
    if (lane == 0) T0s[w] = m4;
    if (t == 0) cnt = 0;
    __syncthreads();
    u64 T0 = T0s[0];
    T0 = T0s[1] > T0 ? T0s[1] : T0;
    T0 = T0s[2] > T0 ? T0s[2] : T0;
    T0 = T0s[3] > T0 ? T0s[3] : T0;

#pragma unroll
    for (int j = 0; j < KK; ++j) {
        if (keys[j] <= T0) {
            int p = atomicAdd(&cnt, 1);
            if (p < KNN_CAP) pool[p] = keys[j];
        }
    }
    __syncthreads();
    int C = cnt < KNN_CAP ? cnt : KNN_CAP;
    if (t < C) {
        u64 me = pool[t];
        int r = 0;
        for (int i = 0; i < C; ++i) r += (pool[i] < me);
        if (r < KK) idx[(size_t)bid * KK + r] = (int)(me & 0xFFFFFFFFu);
    }
}

// ---------------- K2: transpose key/query -> kqT bf16 (8192 x 256) ----------------
__global__ __launch_bounds__(256) void cvtx_kernel(const float* __restrict__ key,
                                                   const float* __restrict__ query,
                                                   ushort_t* __restrict__ kqT) {
    __shared__ float xs[128][65];
    int b = blockIdx.y, n0 = blockIdx.x * 64, t = threadIdx.x;
    for (int h = 0; h < 2; ++h) {
        const float* src = (h ? query : key) + (size_t)b * CC * NN;
        if (h) __syncthreads();
#pragma unroll
        for (int it = 0; it < 32; ++it) {
            int l = it * 256 + t;
            xs[l >> 6][l & 63] = src[(size_t)(l >> 6) * NN + n0 + (l & 63)];
        }
        __syncthreads();
#pragma unroll
        for (int it = 0; it < 8; ++it) {
            int l = it * 256 + t;
            int row = l >> 5, c0 = (l & 31) * 4;
            u16x4 pk;
            pk[0] = f2b(xs[c0][row]);
            pk[1] = f2b(xs[c0 + 1][row]);
            pk[2] = f2b(xs[c0 + 2][row]);
            pk[3] = f2b(xs[c0 + 3][row]);
            *(u16x4*)(kqT + ((size_t)b * NN + n0 + row) * 256 + h * 128 + c0) = pk;
        }
    }
}

// ---------------- K3: generic MFMA GEMM, 128x128 tile ----------------
template <int KLOOP, int ASTR, int EPI, int OSTR>
__global__ __launch_bounds__(256) void gemmT_kernel(const ushort_t* __restrict__ A,
                                                    const ushort_t* __restrict__ Bm,
                                                    const float* __restrict__ bias,
                                                    float* __restrict__ outF,
                                                    ushort_t* __restrict__ outB) {
    __shared__ ushort_t lA[128 * 32];
    __shared__ ushort_t lB[128 * 32];
    int t = threadIdx.x, lane = t & 63, w = t >> 6;
    int wr = w >> 1, wc = w & 1;
    size_t row0 = (size_t)blockIdx.x * 128;
    int col0 = blockIdx.y * 128;
    int m16 = lane & 15, kg = lane >> 4;
    f32x4 acc[4][4];
#pragma unroll
    for (int i = 0; i < 4; ++i)
#pragma unroll
        for (int j = 0; j < 4; ++j) acc[i][j] = (f32x4){0.f, 0.f, 0.f, 0.f};

    const ushort_t* gA = A + (row0 + (size_t)w * 16 + m16) * ASTR + kg * 8;
    const ushort_t* gB = Bm + ((size_t)(col0 + w * 16 + m16)) * KLOOP + kg * 8;
    ushort_t* lA0 = lA + w * 512;
    ushort_t* lB0 = lB + w * 512;
    for (int kt = 0; kt < KLOOP / 32; ++kt) {
        int ko = kt * 32;
        GLDS16(gA + ko, lA0);
        GLDS16(gA + (size_t)64 * ASTR + ko, lA0 + 2048);
        GLDS16(gB + ko, lB0);
        GLDS16(gB + (size_t)64 * KLOOP + ko, lB0 + 2048);
        __syncthreads();
        short8 af[4], bf[4];
#pragma unroll
        for (int i = 0; i < 4; ++i) {
            af[i] = *(const short8*)(lA + ((wr * 4 + i) * 512 + kg * 128 + m16 * 8));
            bf[i] = *(const short8*)(lB + ((wc * 4 + i) * 512 + kg * 128 + m16 * 8));
        }
#pragma unroll
        for (int i = 0; i < 4; ++i)
#pragma unroll
            for (int j = 0; j < 4; ++j)
                acc[i][j] = __builtin_amdgcn_mfma_f32_16x16x32_bf16(af[i], bf[j], acc[i][j], 0, 0, 0);
        __syncthreads();
    }
#pragma unroll
    for (int j = 0; j < 4; ++j) {
        int n = col0 + wc * 64 + j * 16 + m16;
        float bi = bias[n];
#pragma unroll
        for (int i = 0; i < 4; ++i) {
            size_t r = row0 + wr * 64 + i * 16 + kg * 4;
#pragma unroll
            for (int rg = 0; rg < 4; ++rg) {
                float v = acc[i][j][rg] + bi;
                if (EPI == 0) outB[(r + rg) * (size_t)OSTR + n] = f2b(fmaxf(v, 0.f));
                else          outF[(r + rg) * (size_t)OSTR + n] = v;
            }
        }
    }
}

// ---------------- K3b: value = Ws·kq + W2·h1 + b2 + bs (dual-K), fp32+bf16 out ------
__global__ __launch_bounds__(256) void gemmval_kernel(const ushort_t* __restrict__ kqT,
                                                      const ushort_t* __restrict__ h1T,
                                                      const ushort_t* __restrict__ wsb,
                                                      const ushort_t* __restrict__ w2vb,
                                                      const float* __restrict__ b2,
                                                      const float* __restrict__ bs,
                                                      float* __restrict__ valueTf,
                                                      ushort_t* __restrict__ valueTb) {
    __shared__ ushort_t lA[128 * 32];
    __shared__ ushort_t lB[128 * 32];
    int t = threadIdx.x, lane = t & 63, w = t >> 6;
    int wr = w >> 1, wc = w & 1;
    size_t row0 = (size_t)blockIdx.x * 128;
    int m16 = lane & 15, kg = lane >> 4;
    f32x4 acc[4][4];
#pragma unroll
    for (int i = 0; i < 4; ++i)
#pragma unroll
        for (int j = 0; j < 4; ++j) acc[i][j] = (f32x4){0.f, 0.f, 0.f, 0.f};
    ushort_t* lA0 = lA + w * 512;
    ushort_t* lB0 = lB + w * 512;

    {
        const ushort_t* gA = kqT + (row0 + (size_t)w * 16 + m16) * 256 + kg * 8;
        const ushort_t* gB = wsb + ((size_t)(w * 16 + m16)) * 256 + kg * 8;
        for (int kt = 0; kt < 8; ++kt) {
            int ko = kt * 32;
            GLDS16(gA + ko, lA0);
            GLDS16(gA + (size_t)64 * 256 + ko, lA0 + 2048);
            GLDS16(gB + ko, lB0);
            GLDS16(gB + (size_t)64 * 256 + ko, lB0 + 2048);
            __syncthreads();
            short8 af[4], bf[4];
#pragma unroll
            for (int i = 0; i < 4; ++i) {
                af[i] = *(const short8*)(lA + ((wr * 4 + i) * 512 + kg * 128 + m16 * 8));
                bf[i] = *(const short8*)(lB + ((wc * 4 + i) * 512 + kg * 128 + m16 * 8));
            }
#pragma unroll
            for (int i = 0; i < 4; ++i)
#pragma unroll
                for (int j = 0; j < 4; ++j)
                    acc[i][j] = __builtin_amdgcn_mfma_f32_16x16x32_bf16(af[i], bf[j], acc[i][j], 0, 0, 0);
            __syncthreads();
        }
    }
    {
        const ushort_t* gA = h1T + (row0 + (size_t)w * 16 + m16) * 128 + kg * 8;
        const ushort_t* gB = w2vb + ((size_t)(w * 16 + m16)) * 128 + kg * 8;
        for (int kt = 0; kt < 4; ++kt) {
            int ko = kt * 32;
            GLDS16(gA + ko, lA0);
            GLDS16(gA + (size_t)64 * 128 + ko, lA0 + 2048);
            GLDS16(gB + ko, lB0);
            GLDS16(gB + (size_t)64 * 128 + ko, lB0 + 2048);
            __syncthreads();
            short8 af[4], bf[4];
#pragma unroll
            for (int i = 0; i < 4; ++i) {
                af[i] = *(const short8*)(lA + ((wr * 4 + i) * 512 + kg * 128 + m16 * 8));
                bf[i] = *(const short8*)(lB + ((wc * 4 + i) * 512 + kg * 128 + m16 * 8));
            }
#pragma unroll
            for (int i = 0; i < 4; ++i)
#pragma unroll
                for (int j = 0; j < 4; ++j)
                    acc[i][j] = __builtin_amdgcn_mfma_f32_16x16x32_bf16(af[i], bf[j], acc[i][j], 0, 0, 0);
            __syncthreads();
        }
    }
#pragma unroll
    for (int j = 0; j < 4; ++j) {
        int n = wc * 64 + j * 16 + m16;
        float bi = b2[n] + bs[n];
#pragma unroll
        for (int i = 0; i < 4; ++i) {
            size_t r = row0 + wr * 64 + i * 16 + kg * 4;
#pragma unroll
            for (int rg = 0; rg < 4; ++rg) {
                float v = acc[i][j][rg] + bi;
                valueTf[(r + rg) * (size_t)CC + n] = v;
                valueTb[(r + rg) * (size_t)CC + n] = f2b(v);
            }
        }
    }
}

// ---------------- K3c: kT and qT in one launch ----------------
__global__ __launch_bounds__(256) void gemmkq_kernel(const ushort_t* __restrict__ kqT,
                                                     const ushort_t* __restrict__ wkb,
                                                     const ushort_t* __restrict__ wqb,
                                                     const float* __restrict__ bk,
                                                     const float* __restrict__ bq,
                                                     float* __restrict__ kT,
                                                     float* __restrict__ qT) {
    __shared__ ushort_t lA[128 * 32];
    __shared__ ushort_t lB[128 * 32];
    int half = blockIdx.y >> 1;
    int col0 = (blockIdx.y & 1) * 128;
    const ushort_t* A = kqT + half * 128;
    const ushort_t* Bm = half ? wqb : wkb;
    const float* bias = half ? bq : bk;
    float* outF = half ? qT : kT;

    int t = threadIdx.x, lane = t & 63, w = t >> 6;
    int wr = w >> 1, wc = w & 1;
    size_t row0 = (size_t)blockIdx.x * 128;
    int m16 = lane & 15, kg = lane >> 4;
    f32x4 acc[4][4];
#pragma unroll
    for (int i = 0; i < 4; ++i)
#pragma unroll
        for (int j = 0; j < 4; ++j) acc[i][j] = (f32x4){0.f, 0.f, 0.f, 0.f};
    const ushort_t* gA = A + (row0 + (size_t)w * 16 + m16) * 256 + kg * 8;
    const ushort_t* gB = Bm + ((size_t)(col0 + w * 16 + m16)) * 128 + kg * 8;
    ushort_t* lA0 = lA + w * 512;
    ushort_t* lB0 = lB + w * 512;
    for (int kt = 0; kt < 4; ++kt) {
        int ko = kt * 32;
        GLDS16(gA + ko, lA0);
        GLDS16(gA + (size_t)64 * 256 + ko, lA0 + 2048);
        GLDS16(gB + ko, lB0);
        GLDS16(gB + (size_t)64 * 128 + ko, lB0 + 2048);
        __syncthreads();
        short8 af[4], bf[4];
#pragma unroll
        for (int i = 0; i < 4; ++i) {
            af[i] = *(const short8*)(lA + ((wr * 4 + i) * 512 + kg * 128 + m16 * 8));
            bf[i] = *(const short8*)(lB + ((wc * 4 + i) * 512 + kg * 128 + m16 * 8));
        }
#pragma unroll
        for (int i = 0; i < 4; ++i)
#pragma unroll
            for (int j = 0; j < 4; ++j)
                acc[i][j] = __builtin_amdgcn_mfma_f32_16x16x32_bf16(af[i], bf[j], acc[i][j], 0, 0, 0);
        __syncthreads();
    }
#pragma unroll
    for (int j = 0; j < 4; ++j) {
        int n = col0 + wc * 64 + j * 16 + m16;
        float bi = bias[n];
#pragma unroll
        for (int i = 0; i < 4; ++i) {
            size_t r = row0 + wr * 64 + i * 16 + kg * 4;
#pragma unroll
            for (int rg = 0; rg < 4; ++rg)
                outF[(r + rg) * (size_t)DIMD + n] = acc[i][j][rg] + bi;
        }
    }
}

// ---------------- K5: pos_rel first/second moments (9 sums) ----------------
__global__ __launch_bounds__(256) void pos_stats_kernel(const float* __restrict__ pos,
                                                        const int* __restrict__ idx,
                                                        float* __restrict__ stats) {
    int sid = blockIdx.x * 256 + threadIdx.x;
    int b = sid / (NN * KK);
    int r = sid % (NN * KK);
    int n = r / KK;
    int m = idx[sid];
    const float* px = pos + (size_t)b * 3 * NN;
    float dx = px[n] - px[m];
    float dy = px[NN + n] - px[NN + m];
    float dz = px[2 * NN + n] - px[2 * NN + m];
    float v[9] = {dx, dy, dz, dx * dx, dy * dy, dz * dz, dx * dy, dx * dz, dy * dz};
    __shared__ float red[256];
    for (int j = 0; j < 9; ++j) {
        red[threadIdx.x] = v[j];
        __syncthreads();
        for (int off = 128; off >= 1; off >>= 1) {
            if (threadIdx.x < off) red[threadIdx.x] += red[threadIdx.x + off];
            __syncthreads();
        }
        if (threadIdx.x == 0) atomicAdd(&stats[j], red[0]);
        __syncthreads();
    }
}

// ---------------- K6: pos BN affine (a1, a0) per 64 channels ----------------
__global__ void pos_bn_kernel(const float* __restrict__ stats, const float* __restrict__ pw1,
                              const float* __restrict__ pb1, const float* __restrict__ pg1,
                              const float* __restrict__ pbe1, float* __restrict__ posA) {
    int c = threadIdx.x;
    if (c >= PHH) return;
    float M = (float)(BB * NN * KK);
    float mu0 = stats[0] / M, mu1 = stats[1] / M, mu2 = stats[2] / M;
    float E00 = stats[3] / M, E11 = stats[4] / M, E22 = stats[5] / M;
    float E01 = stats[6] / M, E02 = stats[7] / M, E12 = stats[8] / M;
    float w0 = pw1[c * 3], w1 = pw1[c * 3 + 1], w2 = pw1[c * 3 + 2];
    float wmu = w0 * mu0 + w1 * mu1 + w2 * mu2;
    float mean_h = wmu + pb1[c];
    float Eh2 = w0 * w0 * E00 + w1 * w1 * E11 + w2 * w2 * E22
              + 2.f * (w0 * w1 * E01 + w0 * w2 * E02 + w1 * w2 * E12)
              + 2.f * pb1[c] * wmu + pb1[c] * pb1[c];
    float var = Eh2 - mean_h * mean_h;
    float a1 = pg1[c] * rsqrtf(var + EPSF);
    posA[c] = a1;
    posA[PHH + c] = pbe1[c] - mean_h * a1;
}

// ---------------- K7a: P1 = relu(BNaffine(pw1 . pos_rel)) bf16 (M x 64) ----------------
__global__ __launch_bounds__(256) void p1_kernel(const float* __restrict__ pos,
                                                 const int* __restrict__ idx,
                                                 const float* __restrict__ pw1,
                                                 const float* __restrict__ pb1,
                                                 const float* __restrict__ posA,
                                                 ushort_t* __restrict__ p1) {
    int gid = blockIdx.x * 256 + threadIdx.x;
    int samp = gid >> 6, c = gid & 63;
    int p = samp >> 4;
    int b = p >> 12, n = p & (NN - 1);
    int m = idx[samp];
    const float* px = pos + (size_t)b * 3 * NN;
    float dx = px[n] - px[m];
    float dy = px[NN + n] - px[NN + m];
    float dz = px[2 * NN + n] - px[2 * NN + m];
    float h = pw1[c * 3] * dx + pw1[c * 3 + 1] * dy + pw1[c * 3 + 2] * dz + pb1[c];
    p1[gid] = f2b(fmaxf(h * posA[c] + posA[PHH + c], 0.f));
}

// ---------------- K8: mu = column sums of s ----------------
__global__ __launch_bounds__(256) void mu_kernel(const ushort_t* __restrict__ sb16,
                                                 float* __restrict__ mu) {
    int c = threadIdx.x;
    const ushort_t* p = sb16 + (size_t)blockIdx.x * 512 * DIMD + c;
    float acc = 0.f;
    for (int i = 0; i < 512; ++i) acc += b2f(p[(size_t)i * DIMD]);
    atomicAdd(&mu[c], acc);
}

// ---------------- K9: R partials via MFMA ----------------
__global__ __launch_bounds__(256) void rg_kernel(const ushort_t* __restrict__ S,
                                                 float* __restrict__ Rpart) {
    __shared__ ushort_t ls[32 * LSTR];
    int t = threadIdx.x;
    int lane = t & 63, w = t >> 6;
    int wr = w >> 1, wc = w & 1;
    int ti = blockIdx.y >> 1, tj = blockIdx.y & 1;
    int m16 = lane & 15, kg = lane >> 4;
    size_t kbase = (size_t)blockIdx.x * RKCH;

    f32x4 acc[4][4];
#pragma unroll
    for (int i = 0; i < 4; ++i)
#pragma unroll
        for (int j = 0; j < 4; ++j) acc[i][j] = (f32x4){0.f, 0.f, 0.f, 0.f};

    int lm = t >> 3;
    int lc = (t & 7) * 32;
    const ushort_t* gS = S + (kbase + lm) * DIMD + lc;
    ushort_t* lp = ls + lm * LSTR + lc;

    for (int kt = 0; kt < RKCH / 32; ++kt) {
        const ushort_t* gp = gS + (size_t)kt * 32 * DIMD;
        u16x8 v0 = *(const u16x8*)(gp);
        u16x8 v1 = *(const u16x8*)(gp + 8);
        u16x8 v2 = *(const u16x8*)(gp + 16);
        u16x8 v3 = *(const u16x8*)(gp + 24);
        __syncthreads();
#pragma unroll
        for (int q = 0; q < 4; ++q) {
            *(u16x2*)(lp + 0 + 2 * q) = (u16x2){v0[2 * q], v0[2 * q + 1]};
            *(u16x2*)(lp + 8 + 2 * q) = (u16x2){v1[2 * q], v1[2 * q + 1]};
            *(u16x2*)(lp + 16 + 2 * q) = (u16x2){v2[2 * q], v2[2 * q + 1]};
            *(u16x2*)(lp + 24 + 2 * q) = (u16x2){v3[2 * q], v3[2 * q + 1]};
        }
        __syncthreads();
        short8 af[4], bf[4];
#pragma unroll
        for (int i = 0; i < 4; ++i) {
            int chA = ti * 128 + wr * 64 + i * 16 + m16;
            int chB = tj * 128 + wc * 64 + i * 16 + m16;
#pragma unroll
            for (int j = 0; j < 8; ++j) {
                int k = kg * 8 + j;
                af[i][j] = (short)ls[k * LSTR + chA];
                bf[i][j] = (short)ls[k * LSTR + chB];
            }
        }
#pragma unroll
        for (int i = 0; i < 4; ++i)
#pragma unroll
            for (int j = 0; j < 4; ++j)
                acc[i][j] = __builtin_amdgcn_mfma_f32_16x16x32_bf16(af[i], bf[j], acc[i][j], 0, 0, 0);
    }

    float* rp = Rpart + (size_t)blockIdx.x * (DIMD * DIMD);
#pragma unroll
    for (int i = 0; i < 4; ++i) {
        int r0 = ti * 128 + wr * 64 + i * 16 + kg * 4;
#pragma unroll
        for (int j = 0; j < 4; ++j) {
            int cn = tj * 128 + wc * 64 + j * 16 + m16;
#pragma unroll
            for (int rg = 0; rg < 4; ++rg)
                rp[(size_t)(r0 + rg) * DIMD + cn] = acc[i][j][rg];
        }
    }
}

// ---------------- K9b: reduce R partials ----------------
__global__ __launch_bounds__(256) void r_reduce_kernel(const float* __restrict__ Rpart,
                                                       float* __restrict__ R) {
    int e = blockIdx.x * 256 + threadIdx.x;
    float s = 0.f;
    for (int p = 0; p < RSPLIT; ++p) s += Rpart[(size_t)p * (DIMD * DIMD) + e];
    R[e] = s;
}

// ---------------- K10: attn BN -> fused scale/offset per hidden channel ----------------
__global__ __launch_bounds__(256) void attn_bn_kernel(const float* __restrict__ R,
                                                      const float* __restrict__ mu,
                                                      const float* __restrict__ aw1,
                                                      const float* __restrict__ ab1,
                                                      const float* __restrict__ ag1,
                                                      const float* __restrict__ abe1,
                                                      float* __restrict__ attA) {
    int c = blockIdx.x;
    int t = threadIdx.x;
    __shared__ float wsh[DIMD];
    __shared__ float red[DIMD];
    wsh[t] = aw1[(size_t)c * DIMD + t];
    __syncthreads();
    const float* Rr = R + (size_t)t * DIMD;
    float q = 0.f;
#pragma unroll 4
    for (int j = 0; j < DIMD; ++j) q += Rr[j] * wsh[j];
    red[t] = q * wsh[t];
    __syncthreads();
    for (int off = 128; off >= 1; off >>= 1) {
        if (t < off) red[t] += red[t + off];
        __syncthreads();
    }
    float wRw = red[0];
    __syncthreads();
    red[t] = wsh[t] * mu[t];
    __syncthreads();
    for (int off = 128; off >= 1; off >>= 1) {
        if (t < off) red[t] += red[t + off];
        __syncthreads();
    }
    if (t == 0) {
        float M = (float)(BB * NN * KK);
        float wmu = red[0] / M;
        float b1c = ab1[c];
        float Eh = wmu + b1c;
        float Eh2 = wRw / M + 2.f * b1c * wmu + b1c * b1c;
        float var = Eh2 - Eh * Eh;
        float a1 = ag1[c] * rsqrtf(var + EPSF);
        attA[c] = a1;
        attA[AHH + c] = a1 * b1c + abe1[c] - Eh * a1;
    }
}

// ---------------- K10b: convert all weights to bf16 (+ W2 to fp8 x64) ----------------
__global__ void cvt_w_kernel(const float* __restrict__ aw1, const float* __restrict__ aw2,
                             const float* __restrict__ pw2,
                             const float* __restrict__ mw1, const float* __restrict__ mws,
                             const float* __restrict__ mw2,
                             const float* __restrict__ wk, const float* __restrict__ wq,
                             const float* __restrict__ wv,
                             ushort_t* __restrict__ w1b, ushort_t* __restrict__ w2b,
                             ushort_t* __restrict__ pw2b,
                             ushort_t* __restrict__ w1vb, ushort_t* __restrict__ wsvb,
                             ushort_t* __restrict__ w2vb,
                             ushort_t* __restrict__ wkb, ushort_t* __restrict__ wqb,
                             ushort_t* __restrict__ wvb,
                             uchar_t* __restrict__ w2f8) {
    int i = blockIdx.x * 256 + threadIdx.x;
    int o = i;
    if (o < 262144) { w1b[o] = f2b(aw1[o]); return; }   o -= 262144;
    if (o < 262144) { w2b[o] = f2b(aw2[o]); w2f8[o] = f2f8(aw2[o] * 64.f); return; } o -= 262144;
    if (o < 16384)  { pw2b[o] = f2b(pw2[o]); return; }  o -= 16384;
    if (o < 32768)  { w1vb[o] = f2b(mw1[o]); return; }  o -= 32768;
    if (o < 32768)  { wsvb[o] = f2b(mws[o]); return; }  o -= 32768;
    if (o < 16384)  { w2vb[o] = f2b(mw2[o]); return; }  o -= 16384;
    if (o < 32768)  { wkb[o] = f2b(wk[o]); return; }    o -= 32768;
    if (o < 32768)  { wqb[o] = f2b(wq[o]); return; }    o -= 32768;
    if (o < 32768)  { wvb[o] = f2b(wv[o]); }
}

// ---------------- MFMA GEMM (s-build): s = q - k_g + (P1·pw2^T + pb2) ----------------
template <int KDIM>
__global__ __launch_bounds__(256) void gemmS_kernel(const ushort_t* __restrict__ A,
                                                    const ushort_t* __restrict__ Bm,
                                                    const float* __restrict__ p0,
                                                    ushort_t* __restrict__ Sb,
                                                    const float* __restrict__ qT,
                                                    const float* __restrict__ kT,
                                                    const int* __restrict__ gidx) {
    __shared__ ushort_t lA[128 * 32];
    __shared__ ushort_t lB[128 * 32];
    int t = threadIdx.x;
    int lane = t & 63, w = t >> 6;
    int wr = w >> 1, wc = w & 1;
    size_t row0 = (size_t)blockIdx.x * 128;
    int col0 = blockIdx.y * 128;
    int m16 = lane & 15, kg = lane >> 4;

    f32x4 acc[4][4];
#pragma unroll
    for (int i = 0; i < 4; ++i)
#pragma unroll
        for (int j = 0; j < 4; ++j) acc[i][j] = (f32x4){0.f, 0.f, 0.f, 0.f};

    const ushort_t* gA = A + (row0 + (size_t)w * 16 + m16) * KDIM + kg * 8;
    const ushort_t* gB = Bm + ((size_t)(col0 + w * 16 + m16)) * KDIM + kg * 8;
    ushort_t* lA0 = lA + w * 512;
    ushort_t* lB0 = lB + w * 512;

    for (int kt = 0; kt < KDIM / 32; ++kt) {
        int ko = kt * 32;
        GLDS16(gA + ko, lA0);
        GLDS16(gA + (size_t)64 * KDIM + ko, lA0 + 2048);
        GLDS16(gB + ko, lB0);
        GLDS16(gB + (size_t)64 * KDIM + ko, lB0 + 2048);
        __syncthreads();
        short8 af[4], bf[4];
#pragma unroll
        for (int i = 0; i < 4; ++i) {
            af[i] = *(const short8*)(lA + ((wr * 4 + i) * 512 + kg * 128 + m16 * 8));
            bf[i] = *(const short8*)(lB + ((wc * 4 + i) * 512 + kg * 128 + m16 * 8));
        }
#pragma unroll
        for (int i = 0; i < 4; ++i)
#pragma unroll
            for (int j = 0; j < 4; ++j)
                acc[i][j] = __builtin_amdgcn_mfma_f32_16x16x32_bf16(af[i], bf[j], acc[i][j], 0, 0, 0);
        __syncthreads();
    }

    int nn[4]; float bi[4];
#pragma unroll
    for (int j = 0; j < 4; ++j) { nn[j] = col0 + wc * 64 + j * 16 + m16; bi[j] = p0[nn[j]]; }
#pragma unroll
    for (int i = 0; i < 4; ++i) {
        size_t r = row0 + wr * 64 + i * 16 + kg * 4;
#pragma unroll
        for (int rg = 0; rg < 4; ++rg) {
            size_t rr = r + rg;
            int p = (int)(rr >> 4);
            int krow = (p & ~(NN - 1)) + gidx[rr];
            const float* qrow = qT + (size_t)p * DIMD;
            const float* kro = kT + (size_t)krow * DIMD;
#pragma unroll
            for (int j = 0; j < 4; ++j) {
                float sv = qrow[nn[j]] - kro[nn[j]] + acc[i][j][rg] + bi[j];
                Sb[rr * (size_t)DIMD + nn[j]] = f2b(sv);
            }
        }
    }
}

// ---------------- K11: fused attn MLP + softmax + aggregation (v6) ----------------
// No lS: GEMM1 A- and B-fragments both read straight from global/L2 (frag = 16 B
// contiguous run of row-major S). Double-buffered 8 KB fp8 lHt -> ONE barrier per
// jc (8 total, was 16). LDS 37 KB (lgB epilogue overlay) -> 4 blocks/CU.
__global__ __launch_bounds__(256, 3) void fused_mlp_kernel(const ushort_t* __restrict__ S,
                                                        const ushort_t* __restrict__ w1b,
                                                        const uchar_t* __restrict__ w2f8,
                                                        const float* __restrict__ attA,
                                                        const float* __restrict__ ab2,
                                                        const int* __restrict__ idx,
                                                        const float* __restrict__ qT,
                                                        const float* __restrict__ kT,
                                                        const float* __restrict__ vT,
                                                        float* __restrict__ aggT) {
    __shared__ char smem[36992];
    uchar_t*  lHt = (uchar_t*)smem;              // 2 x 8 KB fp8 H, frag layout
    ushort_t* lgB = (ushort_t*)smem;             // epilogue overlay: 256 out x 64 smp bf16, stride 72

    int t = threadIdx.x;
    int lane = t & 63, w = t >> 6;
    int m16 = lane & 15, kg = lane >> 4;
    size_t row0 = (size_t)blockIdx.x * 64;

    f32x4 acc2[4][4];
#pragma unroll
    for (int i = 0; i < 4; ++i)
#pragma unroll
        for (int j = 0; j < 4; ++j) acc2[i][j] = (f32x4){0.f, 0.f, 0.f, 0.f};

    const ushort_t* Sfrag = S + (row0 + m16) * DIMD + kg * 8;   // + sj*16*DIMD + kt*32

    for (int jc = 0; jc < 8; ++jc) {
        uchar_t* buf = lHt + (jc & 1) * 8192;
        f32x4 acc1[2][4];
#pragma unroll
        for (int hi = 0; hi < 2; ++hi)
#pragma unroll
            for (int sj = 0; sj < 4; ++sj) acc1[hi][sj] = (f32x4){0.f, 0.f, 0.f, 0.f};
#pragma unroll
        for (int kt = 0; kt < 8; ++kt) {
            short8 af[2], bf[4];
#pragma unroll
            for (int hi = 0; hi < 2; ++hi)
                af[hi] = *(const short8*)(w1b + ((size_t)(jc * 128 + w * 32 + hi * 16 + m16)) * DIMD + kt * 32 + kg * 8);
#pragma unroll
            for (int sj = 0; sj < 4; ++sj)
                bf[sj] = *(const short8*)(Sfrag + (size_t)sj * 16 * DIMD + kt * 32);
#pragma unroll
            for (int hi = 0; hi < 2; ++hi)
#pragma unroll
                for (int sj = 0; sj < 4; ++sj)
                    acc1[hi][sj] = __builtin_amdgcn_mfma_f32_16x16x32_bf16(af[hi], bf[sj], acc1[hi][sj], 0, 0, 0);
        }
        // affine + relu + fp8 pack into buf (frag layout, byte units, stride 128).
        // Write of buf[jc&1] at jc>=2 is safe: barrier at jc-1 ordered all GEMM2
        // reads of jc-2 (same buffer) before it.
#pragma unroll
        for (int hi = 0; hi < 2; ++hi) {
            float4 sc4 = *(const float4*)(attA + jc * 128 + w * 32 + hi * 16 + kg * 4);
            float4 of4 = *(const float4*)(attA + AHH + jc * 128 + w * 32 + hi * 16 + kg * 4);
#pragma unroll
            for (int sj = 0; sj < 4; ++sj) {
                float h0 = fmaxf(sc4.x * acc1[hi][sj][0] + of4.x, 0.f);
                float h1 = fmaxf(sc4.y * acc1[hi][sj][1] + of4.y, 0.f);
                float h2 = fmaxf(sc4.z * acc1[hi][sj][2] + of4.z, 0.f);
                float h3 = fmaxf(sc4.w * acc1[hi][sj][3] + of4.w, 0.f);
                int p01 = __builtin_amdgcn_cvt_pk_fp8_f32(h0, h1, 0, false);
                int pk = __builtin_amdgcn_cvt_pk_fp8_f32(h2, h3, p01, true);
                int ah = (w * 4 + sj) * 512 + (hi * 2 + (kg >> 1)) * 128 + m16 * 8 + (kg & 1) * 4;
                *(int*)(buf + ah) = pk;
            }
        }
        __syncthreads();
        // GEMM2 (fp8): wave w -> out slice w*64..w*64+63 x 64 samples
#pragma unroll
        for (int g = 0; g < 4; ++g) {
            i64 af2[4], bf2[4];
#pragma unroll
            for (int oi = 0; oi < 4; ++oi)
                af2[oi] = *(const i64*)(w2f8 + ((size_t)(w * 64 + oi * 16 + m16)) * AHH + jc * 128 + g * 32 + kg * 8);
#pragma unroll
            for (int sj = 0; sj < 4; ++sj)
                bf2[sj] = *(const i64*)(buf + (g * 4 + sj) * 512 + kg * 128 + m16 * 8);
#pragma unroll
            for (int oi = 0; oi < 4; ++oi)
#pragma unroll
                for (int sj = 0; sj < 4; ++sj)
                    acc2[oi][sj] = __builtin_amdgcn_mfma_f32_16x16x32_fp8_fp8(af2[oi], bf2[sj], acc2[oi][sj], 0, 0, 0);
        }
    }
    __syncthreads();   // last GEMM2 reads done before lgB overlays lHt

    // phase 1: logits (acc2/64 + b2) -> lgB[out][smp] (bf16, stride 72)
    const float invsc = 0.015625f;
#pragma unroll
    for (int oi = 0; oi < 4; ++oi) {
        int ob = w * 64 + oi * 16 + kg * 4;
        float4 b2v = *(const float4*)(ab2 + ob);
#pragma unroll
        for (int sj = 0; sj < 4; ++sj) {
            int smp = sj * 16 + m16;
            lgB[(ob + 0) * 72 + smp] = f2b(acc2[oi][sj][0] * invsc + b2v.x);
            lgB[(ob + 1) * 72 + smp] = f2b(acc2[oi][sj][1] * invsc + b2v.y);
            lgB[(ob + 2) * 72 + smp] = f2b(acc2[oi][sj][2] * invsc + b2v.z);
            lgB[(ob + 3) * 72 + smp] = f2b(acc2[oi][sj][3] * invsc + b2v.w);
        }
    }
    __syncthreads();

    // phase 2: thread t owns out-channel t; 4 points; serial softmax in regs.
    int out = t;
    for (int pt = 0; pt < 4; ++pt) {
        int pid = (int)(row0 >> 4) + pt;
        u16x8 v0 = *(const u16x8*)(lgB + out * 72 + pt * 16);
        u16x8 v1 = *(const u16x8*)(lgB + out * 72 + pt * 16 + 8);
        float lg[KK];
#pragma unroll
        for (int s = 0; s < 8; ++s) { lg[s] = b2f(v0[s]); lg[s + 8] = b2f(v1[s]); }
        float mx = lg[0];
#pragma unroll
        for (int s = 1; s < KK; ++s) mx = fmaxf(mx, lg[s]);
        float se = 0.f;
#pragma unroll
        for (int s = 0; s < KK; ++s) { lg[s] = expf(lg[s] - mx); se += lg[s]; }
        float inv = 1.f / se;
        int base = pid & ~(NN - 1);
        float acc = 0.f;
#pragma unroll
        for (int s = 0; s < KK; ++s) {
            int row = pid * KK + s;
            int krow = base + idx[row];
            float sv = b2f(S[(size_t)row * DIMD + out]);
            float kv = kT[(size_t)krow * DIMD + out];
            acc += lg[s] * (sv + kv);
        }
        float vf = vT[(size_t)pid * DIMD + out];
        float q  = qT[(size_t)pid * DIMD + out];
        aggT[(size_t)pid * DIMD + out] = vf - q + acc * inv;
    }
}

// ---------------- K12: y = we·agg + be + value (both LDS-staged, coalesced) --------
__global__ __launch_bounds__(256) void final_kernel(const float* __restrict__ aggT,
                                                    const float* __restrict__ we,
                                                    const float* __restrict__ be,
                                                    const float* __restrict__ valueTf,
                                                    float* __restrict__ out) {
    __shared__ float xs[2 * FPT][DIMD];
    __shared__ float vs[2 * FPT][CC];
    int b = blockIdx.y;
    int n0 = blockIdx.x * (2 * FPT);
    int t = threadIdx.x;
    const float4* src = (const float4*)(aggT + ((size_t)b * NN + n0) * DIMD);
    float4* dst = (float4*)xs;
#pragma unroll
    for (int l = 0; l < (2 * FPT * DIMD / 4) / 256; ++l) dst[t + 256 * l] = src[t + 256 * l];
    const float4* src2 = (const float4*)(valueTf + ((size_t)b * NN + n0) * CC);
    float4* dst2 = (float4*)vs;
#pragma unroll
    for (int l = 0; l < (2 * FPT * CC / 4) / 256; ++l) dst2[t + 256 * l] = src2[t + 256 * l];
    __syncthreads();
    int o = t & 127, ph = t >> 7;
    float acc[FPT];
#pragma unroll
    for (int p = 0; p < FPT; ++p) acc[p] = 0.f;
    const float4* wr = (const float4*)(we + (size_t)o * DIMD);
#pragma unroll 8
    for (int i4 = 0; i4 < DIMD / 4; ++i4) {
        float4 w4 = wr[i4];
#pragma unroll
        for (int p = 0; p < FPT; ++p) {
            float4 x4 = *(const float4*)&xs[ph * FPT + p][i4 * 4];
            acc[p] += w4.x * x4.x + w4.y * x4.y + w4.z * x4.z + w4.w * x4.w;
        }
    }
    float bo = be[o];
#pragma unroll
    for (int p = 0; p < FPT; ++p) {
        size_t oi = ((size_t)b * CC + o) * NN + n0 + ph * FPT + p;
        out[oi] = acc[p] + bo + vs[ph * FPT + p][o];
    }
}

extern "C" void kernel_launch(void* const* d_in, const int* in_sizes, int n_in,
                              void* d_out, int out_size, void* d_ws, size_t ws_size,
                              hipStream_t stream) {
    (void)in_sizes; (void)n_in; (void)out_size; (void)ws_size;
    const float* pos     = (const float*)d_in[0];
    const float* key     = (const float*)d_in[1];
    const float* query   = (const float*)d_in[2];
    const float* mlpv_w1 = (const float*)d_in[3];
    const float* mlpv_b1 = (const float*)d_in[4];
    const float* mlpv_w2 = (const float*)d_in[5];
    const float* mlpv_b2 = (const float*)d_in[6];
    const float* mlpv_ws = (const float*)d_in[7];
    const float* mlpv_bs = (const float*)d_in[8];
    const float* wk  = (const float*)d_in[9];
    const float* bk  = (const float*)d_in[10];
    const float* wq  = (const float*)d_in[11];
    const float* bq  = (const float*)d_in[12];
    const float* wv  = (const float*)d_in[13];
    const float* bv  = (const float*)d_in[14];
    const float* pw1 = (const float*)d_in[15];
    const float* pb1 = (const float*)d_in[16];
    const float* pg1 = (const float*)d_in[17];
    const float* pbe1= (const float*)d_in[18];
    const float* pw2 = (const float*)d_in[19];
    const float* pb2 = (const float*)d_in[20];
    const float* aw1 = (const float*)d_in[21];
    const float* ab1 = (const float*)d_in[22];
    const float* ag1 = (const float*)d_in[23];
    const float* abe1= (const float*)d_in[24];
    const float* aw2 = (const float*)d_in[25];
    const float* ab2 = (const float*)d_in[26];
    const float* we  = (const float*)d_in[27];
    const float* be  = (const float*)d_in[28];
    float* out = (float*)d_out;

    char* wsb = (char*)d_ws;
    size_t off = 0;
    auto alloc = [&](size_t bytes) {
        void* p = wsb + off;
        off += (bytes + 255) & ~(size_t)255;
        return p;
    };
    const size_t M = (size_t)BB * NN * KK;   // 131072 rows
    const size_t P = (size_t)BB * NN;        // 8192 points
    int*   idx   = (int*)  alloc(M * 4);
    ushort_t* kqT     = (ushort_t*)alloc(P * 256 * 2);
    ushort_t* h1T     = (ushort_t*)alloc(P * CC * 2);
    float*    valueTf = (float*)   alloc(P * CC * 4);
    ushort_t* valueTb = (ushort_t*)alloc(P * CC * 2);
    float* kT    = (float*)alloc(P * DIMD * 4);
    float* qT    = (float*)alloc(P * DIMD * 4);
    float* vT    = (float*)alloc(P * DIMD * 4);
    float* aggT  = (float*)alloc(P * DIMD * 4);
    float* zero0 = (float*)alloc((size_t)(16 + 256 + 65536) * 4);
    float* stats = zero0;
    float* mu    = zero0 + 16;
    float* R     = zero0 + 16 + 256;
    float* posA  = (float*)alloc((size_t)2 * PHH * 4);
    float* attA  = (float*)alloc((size_t)2 * AHH * 4);
    ushort_t* w1b  = (ushort_t*)alloc((size_t)AHH * DIMD * 2);
    ushort_t* w2b  = (ushort_t*)alloc((size_t)DIMD * AHH * 2);
    uchar_t*  w2f8 = (uchar_t*) alloc((size_t)DIMD * AHH);
    ushort_t* pw2b = (ushort_t*)alloc((size_t)DIMD * PHH * 2);
    ushort_t* w1vb = (ushort_t*)alloc((size_t)CC * 256 * 2);
    ushort_t* wsvb = (ushort_t*)alloc((size_t)CC * 256 * 2);
    ushort_t* w2vb = (ushort_t*)alloc((size_t)CC * CC * 2);
    ushort_t* wkb  = (ushort_t*)alloc((size_t)DIMD * CC * 2);
    ushort_t* wqb  = (ushort_t*)alloc((size_t)DIMD * CC * 2);
    ushort_t* wvb  = (ushort_t*)alloc((size_t)DIMD * CC * 2);
    ushort_t* sb16 = (ushort_t*)alloc(M * DIMD * 2);          //  67 MB
    char* ovl = (char*)alloc((size_t)RSPLIT * DIMD * DIMD * 4);
    ushort_t* p1buf = (ushort_t*)ovl;
    float*    Rpart = (float*)ovl;

    int ZN = 16 + 256 + 65536;
    zero_kernel<<<(ZN + 255) / 256, 256, 0, stream>>>(zero0, ZN);
    knn_kernel<<<BB * NN, 256, 0, stream>>>(pos, idx);
    cvt_w_kernel<<<(720896 + 255) / 256, 256, 0, stream>>>(aw1, aw2, pw2, mlpv_w1, mlpv_ws, mlpv_w2,
                                                           wk, wq, wv, w1b, w2b, pw2b,
                                                           w1vb, wsvb, w2vb, wkb, wqb, wvb, w2f8);
    cvtx_kernel<<<dim3(NN / 64, BB), 256, 0, stream>>>(key, query, kqT);
    gemmT_kernel<256, 256, 0, 128><<<dim3(P / 128, 1), 256, 0, stream>>>(kqT, w1vb, mlpv_b1, nullptr, h1T);
    gemmval_kernel<<<dim3(P / 128, 1), 256, 0, stream>>>(kqT, h1T, wsvb, w2vb, mlpv_b2, mlpv_bs, valueTf, valueTb);
    gemmkq_kernel<<<dim3(P / 128, 4), 256, 0, stream>>>(kqT, wkb, wqb, bk, bq, kT, qT);
    gemmT_kernel<128, 128, 1, 256><<<dim3(P / 128, 2), 256, 0, stream>>>(valueTb, wvb, bv, vT, nullptr);
    pos_stats_kernel<<<BB * NN * KK / 256, 256, 0, stream>>>(pos, idx, stats);
    pos_bn_kernel<<<1, 64, 0, stream>>>(stats, pw1, pb1, pg1, pbe1, posA);
    p1_kernel<<<(int)(M * PHH / 256), 256, 0, stream>>>(pos, idx, pw1, pb1, posA, p1buf);
    gemmS_kernel<PHH><<<dim3(M / 128, DIMD / 128), 256, 0, stream>>>(p1buf, pw2b, pb2, sb16, qT, kT, idx);
    mu_kernel<<<M / 512, 256, 0, stream>>>(sb16, mu);
    rg_kernel<<<dim3(RSPLIT, 4), 256, 0, stream>>>(sb16, Rpart);
    r_reduce_kernel<<<DIMD * DIMD / 256, 256, 0, stream>>>(Rpart, R);
    attn_bn_kernel<<<AHH, DIMD, 0, stream>>>(R, mu, aw1, ab1, ag1, abe1, attA);
    fused_mlp_kernel<<<(int)(M / 64), 256, 0, stream>>>(sb16, w1b, w2f8, attA, ab2, idx, qT, kT, vT, aggT);
    final_kernel<<<dim3(NN / (2 * FPT), BB), 256, 0, stream>>>(aggT, we, be, valueTf, out);
}

// Round 14
// 684.437 us; speedup vs baseline: 1.3505x; 1.3505x over previous
//
#include <hip/hip_runtime.h>
#include <math.h>

#define BB 2
#define CC 128
#define NN 4096
#define KK 16
#define DIMD 256
#define PHH 64
#define AHH 1024
#define EPSF 1e-5f
#define RSPLIT 128
#define RKCH ((BB * NN * KK) / RSPLIT)   // 1024 samples per R block
#define LSTR 258    // LDS row stride (halfwords): conflict-free transposed gathers
#define KNN_CAP 512
#define FPT 8       // final_kernel points per thread

typedef unsigned short ushort_t;
typedef unsigned char uchar_t;
typedef unsigned long long u64;
typedef long long i64;
typedef __attribute__((ext_vector_type(8))) short short8;
typedef __attribute__((ext_vector_type(8))) unsigned short u16x8;
typedef __attribute__((ext_vector_type(4))) unsigned short u16x4;
typedef __attribute__((ext_vector_type(2))) unsigned short u16x2;
typedef __attribute__((ext_vector_type(4))) float f32x4;

__device__ __forceinline__ ushort_t f2b(float x) {
    union { float f; unsigned u; } v; v.f = x;
    unsigned r = v.u + 0x7fff + ((v.u >> 16) & 1);
    return (ushort_t)(r >> 16);
}
__device__ __forceinline__ float b2f(ushort_t x) {
    union { unsigned u; float f; } v; v.u = ((unsigned)x) << 16;
    return v.f;
}
__device__ __forceinline__ unsigned fsort(float x) {
    union { float f; unsigned u; } v; v.f = x;
    return v.u ^ ((v.u >> 31) ? 0xFFFFFFFFu : 0x80000000u);
}
__device__ __forceinline__ uchar_t f2f8(float x) {
    int p = __builtin_amdgcn_cvt_pk_fp8_f32(x, x, 0, false);
    return (uchar_t)(p & 0xFF);
}

#define GLDS16(gp, lp) __builtin_amdgcn_global_load_lds( \
    (const __attribute__((address_space(1))) void*)(gp), \
    (__attribute__((address_space(3))) void*)(lp), 16, 0, 0)

// ---------------- K0: zero scratch accumulators ----------------
__global__ void zero_kernel(float* p, int n) {
    int i = blockIdx.x * blockDim.x + threadIdx.x;
    if (i < n) p[i] = 0.f;
}

// ---------------- K1: exact kNN via u64-key threshold select ----------------
__global__ __launch_bounds__(256) void knn_kernel(const float* __restrict__ pos,
                                                  int* __restrict__ idx) {
    int bid = blockIdx.x;
    int b = bid / NN, n = bid % NN;
    int t = threadIdx.x;
    int lane = t & 63, w = t >> 6;
    const float* px = pos + (size_t)b * 3 * NN;
    const float* py = px + NN;
    const float* pz = px + 2 * NN;
    float qx = px[n], qy = py[n], qz = pz[n];
    float qs = qx * qx + qy * qy + qz * qz;

    u64 keys[KK];
    u64 lmin = ~0ull;
#pragma unroll
    for (int j = 0; j < KK; ++j) {
        int m = t + 256 * j;
        float mx = px[m], my = py[m], mz = pz[m];
        float ms = mx * mx + my * my + mz * mz;
        float dt = qx * mx + qy * my + qz * mz;
        float d = qs + ms - 2.f * dt;
        u64 k = ((u64)fsort(d) << 32) | (unsigned)m;
        keys[j] = k;
        lmin = k < lmin ? k : lmin;
    }

    __shared__ u64 T0s[4];
    __shared__ u64 pool[KNN_CAP];
    __shared__ int cnt;

    u64 k = lmin, m4 = 0;
#pragma unroll
    for (int r = 0; r < 4; ++r) {
        u64 mv = k;
#pragma unroll
        for (int off = 32; off >= 1; off >>= 1) {
            u64 o = __shfl_xor(mv, off);
            mv = o < mv ? o : mv;
        }
        if (r == 3) m4 = mv;
        if (k == mv) k = ~0ull;
    }
    if (lane == 0) T0s[w] = m4;
    if (t == 0) cnt = 0;
    __syncthreads();
    u64 T0 = T0s[0];
    T0 = T0s[1] > T0 ? T0s[1] : T0;
    T0 = T0s[2] > T0 ? T0s[2] : T0;
    T0 = T0s[3] > T0 ? T0s[3] : T0;

#pragma unroll
    for (int j = 0; j < KK; ++j) {
        if (keys[j] <= T0) {
            int p = atomicAdd(&cnt, 1);
            if (p < KNN_CAP) pool[p] = keys[j];
        }
    }
    __syncthreads();
    int C = cnt < KNN_CAP ? cnt : KNN_CAP;
    if (t < C) {
        u64 me = pool[t];
        int r = 0;
        for (int i = 0; i < C; ++i) r += (pool[i] < me);
        if (r < KK) idx[(size_t)bid * KK + r] = (int)(me & 0xFFFFFFFFu);
    }
}

// ---------------- K2: transpose key/query -> kqT bf16 (8192 x 256) ----------------
__global__ __launch_bounds__(256) void cvtx_kernel(const float* __restrict__ key,
                                                   const float* __restrict__ query,
                                                   ushort_t* __restrict__ kqT) {
    __shared__ float xs[128][65];
    int b = blockIdx.y, n0 = blockIdx.x * 64, t = threadIdx.x;
    for (int h = 0; h < 2; ++h) {
        const float* src = (h ? query : key) + (size_t)b * CC * NN;
        if (h) __syncthreads();
#pragma unroll
        for (int it = 0; it < 32; ++it) {
            int l = it * 256 + t;
            xs[l >> 6][l & 63] = src[(size_t)(l >> 6) * NN + n0 + (l & 63)];
        }
        __syncthreads();
#pragma unroll
        for (int it = 0; it < 8; ++it) {
            int l = it * 256 + t;
            int row = l >> 5, c0 = (l & 31) * 4;
            u16x4 pk;
            pk[0] = f2b(xs[c0][row]);
            pk[1] = f2b(xs[c0 + 1][row]);
            pk[2] = f2b(xs[c0 + 2][row]);
            pk[3] = f2b(xs[c0 + 3][row]);
            *(u16x4*)(kqT + ((size_t)b * NN + n0 + row) * 256 + h * 128 + c0) = pk;
        }
    }
}

// ---------------- K3: generic MFMA GEMM, 128x128 tile ----------------
template <int KLOOP, int ASTR, int EPI, int OSTR>
__global__ __launch_bounds__(256) void gemmT_kernel(const ushort_t* __restrict__ A,
                                                    const ushort_t* __restrict__ Bm,
                                                    const float* __restrict__ bias,
                                                    float* __restrict__ outF,
                                                    ushort_t* __restrict__ outB) {
    __shared__ ushort_t lA[128 * 32];
    __shared__ ushort_t lB[128 * 32];
    int t = threadIdx.x, lane = t & 63, w = t >> 6;
    int wr = w >> 1, wc = w & 1;
    size_t row0 = (size_t)blockIdx.x * 128;
    int col0 = blockIdx.y * 128;
    int m16 = lane & 15, kg = lane >> 4;
    f32x4 acc[4][4];
#pragma unroll
    for (int i = 0; i < 4; ++i)
#pragma unroll
        for (int j = 0; j < 4; ++j) acc[i][j] = (f32x4){0.f, 0.f, 0.f, 0.f};

    const ushort_t* gA = A + (row0 + (size_t)w * 16 + m16) * ASTR + kg * 8;
    const ushort_t* gB = Bm + ((size_t)(col0 + w * 16 + m16)) * KLOOP + kg * 8;
    ushort_t* lA0 = lA + w * 512;
    ushort_t* lB0 = lB + w * 512;
    for (int kt = 0; kt < KLOOP / 32; ++kt) {
        int ko = kt * 32;
        GLDS16(gA + ko, lA0);
        GLDS16(gA + (size_t)64 * ASTR + ko, lA0 + 2048);
        GLDS16(gB + ko, lB0);
        GLDS16(gB + (size_t)64 * KLOOP + ko, lB0 + 2048);
        __syncthreads();
        short8 af[4], bf[4];
#pragma unroll
        for (int i = 0; i < 4; ++i) {
            af[i] = *(const short8*)(lA + ((wr * 4 + i) * 512 + kg * 128 + m16 * 8));
            bf[i] = *(const short8*)(lB + ((wc * 4 + i) * 512 + kg * 128 + m16 * 8));
        }
#pragma unroll
        for (int i = 0; i < 4; ++i)
#pragma unroll
            for (int j = 0; j < 4; ++j)
                acc[i][j] = __builtin_amdgcn_mfma_f32_16x16x32_bf16(af[i], bf[j], acc[i][j], 0, 0, 0);
        __syncthreads();
    }
#pragma unroll
    for (int j = 0; j < 4; ++j) {
        int n = col0 + wc * 64 + j * 16 + m16;
        float bi = bias[n];
#pragma unroll
        for (int i = 0; i < 4; ++i) {
            size_t r = row0 + wr * 64 + i * 16 + kg * 4;
#pragma unroll
            for (int rg = 0; rg < 4; ++rg) {
                float v = acc[i][j][rg] + bi;
                if (EPI == 0) outB[(r + rg) * (size_t)OSTR + n] = f2b(fmaxf(v, 0.f));
                else          outF[(r + rg) * (size_t)OSTR + n] = v;
            }
        }
    }
}

// ---------------- K3b: value = Ws·kq + W2·h1 + b2 + bs (dual-K), fp32+bf16 out ------
__global__ __launch_bounds__(256) void gemmval_kernel(const ushort_t* __restrict__ kqT,
                                                      const ushort_t* __restrict__ h1T,
                                                      const ushort_t* __restrict__ wsb,
                                                      const ushort_t* __restrict__ w2vb,
                                                      const float* __restrict__ b2,
                                                      const float* __restrict__ bs,
                                                      float* __restrict__ valueTf,
                                                      ushort_t* __restrict__ valueTb) {
    __shared__ ushort_t lA[128 * 32];
    __shared__ ushort_t lB[128 * 32];
    int t = threadIdx.x, lane = t & 63, w = t >> 6;
    int wr = w >> 1, wc = w & 1;
    size_t row0 = (size_t)blockIdx.x * 128;
    int m16 = lane & 15, kg = lane >> 4;
    f32x4 acc[4][4];
#pragma unroll
    for (int i = 0; i < 4; ++i)
#pragma unroll
        for (int j = 0; j < 4; ++j) acc[i][j] = (f32x4){0.f, 0.f, 0.f, 0.f};
    ushort_t* lA0 = lA + w * 512;
    ushort_t* lB0 = lB + w * 512;

    {
        const ushort_t* gA = kqT + (row0 + (size_t)w * 16 + m16) * 256 + kg * 8;
        const ushort_t* gB = wsb + ((size_t)(w * 16 + m16)) * 256 + kg * 8;
        for (int kt = 0; kt < 8; ++kt) {
            int ko = kt * 32;
            GLDS16(gA + ko, lA0);
            GLDS16(gA + (size_t)64 * 256 + ko, lA0 + 2048);
            GLDS16(gB + ko, lB0);
            GLDS16(gB + (size_t)64 * 256 + ko, lB0 + 2048);
            __syncthreads();
            short8 af[4], bf[4];
#pragma unroll
            for (int i = 0; i < 4; ++i) {
                af[i] = *(const short8*)(lA + ((wr * 4 + i) * 512 + kg * 128 + m16 * 8));
                bf[i] = *(const short8*)(lB + ((wc * 4 + i) * 512 + kg * 128 + m16 * 8));
            }
#pragma unroll
            for (int i = 0; i < 4; ++i)
#pragma unroll
                for (int j = 0; j < 4; ++j)
                    acc[i][j] = __builtin_amdgcn_mfma_f32_16x16x32_bf16(af[i], bf[j], acc[i][j], 0, 0, 0);
            __syncthreads();
        }
    }
    {
        const ushort_t* gA = h1T + (row0 + (size_t)w * 16 + m16) * 128 + kg * 8;
        const ushort_t* gB = w2vb + ((size_t)(w * 16 + m16)) * 128 + kg * 8;
        for (int kt = 0; kt < 4; ++kt) {
            int ko = kt * 32;
            GLDS16(gA + ko, lA0);
            GLDS16(gA + (size_t)64 * 128 + ko, lA0 + 2048);
            GLDS16(gB + ko, lB0);
            GLDS16(gB + (size_t)64 * 128 + ko, lB0 + 2048);
            __syncthreads();
            short8 af[4], bf[4];
#pragma unroll
            for (int i = 0; i < 4; ++i) {
                af[i] = *(const short8*)(lA + ((wr * 4 + i) * 512 + kg * 128 + m16 * 8));
                bf[i] = *(const short8*)(lB + ((wc * 4 + i) * 512 + kg * 128 + m16 * 8));
            }
#pragma unroll
            for (int i = 0; i < 4; ++i)
#pragma unroll
                for (int j = 0; j < 4; ++j)
                    acc[i][j] = __builtin_amdgcn_mfma_f32_16x16x32_bf16(af[i], bf[j], acc[i][j], 0, 0, 0);
            __syncthreads();
        }
    }
#pragma unroll
    for (int j = 0; j < 4; ++j) {
        int n = wc * 64 + j * 16 + m16;
        float bi = b2[n] + bs[n];
#pragma unroll
        for (int i = 0; i < 4; ++i) {
            size_t r = row0 + wr * 64 + i * 16 + kg * 4;
#pragma unroll
            for (int rg = 0; rg < 4; ++rg) {
                float v = acc[i][j][rg] + bi;
                valueTf[(r + rg) * (size_t)CC + n] = v;
                valueTb[(r + rg) * (size_t)CC + n] = f2b(v);
            }
        }
    }
}

// ---------------- K3c: kT and qT in one launch ----------------
__global__ __launch_bounds__(256) void gemmkq_kernel(const ushort_t* __restrict__ kqT,
                                                     const ushort_t* __restrict__ wkb,
                                                     const ushort_t* __restrict__ wqb,
                                                     const float* __restrict__ bk,
                                                     const float* __restrict__ bq,
                                                     float* __restrict__ kT,
                                                     float* __restrict__ qT) {
    __shared__ ushort_t lA[128 * 32];
    __shared__ ushort_t lB[128 * 32];
    int half = blockIdx.y >> 1;
    int col0 = (blockIdx.y & 1) * 128;
    const ushort_t* A = kqT + half * 128;
    const ushort_t* Bm = half ? wqb : wkb;
    const float* bias = half ? bq : bk;
    float* outF = half ? qT : kT;

    int t = threadIdx.x, lane = t & 63, w = t >> 6;
    int wr = w >> 1, wc = w & 1;
    size_t row0 = (size_t)blockIdx.x * 128;
    int m16 = lane & 15, kg = lane >> 4;
    f32x4 acc[4][4];
#pragma unroll
    for (int i = 0; i < 4; ++i)
#pragma unroll
        for (int j = 0; j < 4; ++j) acc[i][j] = (f32x4){0.f, 0.f, 0.f, 0.f};
    const ushort_t* gA = A + (row0 + (size_t)w * 16 + m16) * 256 + kg * 8;
    const ushort_t* gB = Bm + ((size_t)(col0 + w * 16 + m16)) * 128 + kg * 8;
    ushort_t* lA0 = lA + w * 512;
    ushort_t* lB0 = lB + w * 512;
    for (int kt = 0; kt < 4; ++kt) {
        int ko = kt * 32;
        GLDS16(gA + ko, lA0);
        GLDS16(gA + (size_t)64 * 256 + ko, lA0 + 2048);
        GLDS16(gB + ko, lB0);
        GLDS16(gB + (size_t)64 * 128 + ko, lB0 + 2048);
        __syncthreads();
        short8 af[4], bf[4];
#pragma unroll
        for (int i = 0; i < 4; ++i) {
            af[i] = *(const short8*)(lA + ((wr * 4 + i) * 512 + kg * 128 + m16 * 8));
            bf[i] = *(const short8*)(lB + ((wc * 4 + i) * 512 + kg * 128 + m16 * 8));
        }
#pragma unroll
        for (int i = 0; i < 4; ++i)
#pragma unroll
            for (int j = 0; j < 4; ++j)
                acc[i][j] = __builtin_amdgcn_mfma_f32_16x16x32_bf16(af[i], bf[j], acc[i][j], 0, 0, 0);
        __syncthreads();
    }
#pragma unroll
    for (int j = 0; j < 4; ++j) {
        int n = col0 + wc * 64 + j * 16 + m16;
        float bi = bias[n];
#pragma unroll
        for (int i = 0; i < 4; ++i) {
            size_t r = row0 + wr * 64 + i * 16 + kg * 4;
#pragma unroll
            for (int rg = 0; rg < 4; ++rg)
                outF[(r + rg) * (size_t)DIMD + n] = acc[i][j][rg] + bi;
        }
    }
}

// ---------------- K5: pos_rel first/second moments (9 sums) ----------------
__global__ __launch_bounds__(256) void pos_stats_kernel(const float* __restrict__ pos,
                                                        const int* __restrict__ idx,
                                                        float* __restrict__ stats) {
    int sid = blockIdx.x * 256 + threadIdx.x;
    int b = sid / (NN * KK);
    int r = sid % (NN * KK);
    int n = r / KK;
    int m = idx[sid];
    const float* px = pos + (size_t)b * 3 * NN;
    float dx = px[n] - px[m];
    float dy = px[NN + n] - px[NN + m];
    float dz = px[2 * NN + n] - px[2 * NN + m];
    float v[9] = {dx, dy, dz, dx * dx, dy * dy, dz * dz, dx * dy, dx * dz, dy * dz};
    __shared__ float red[256];
    for (int j = 0; j < 9; ++j) {
        red[threadIdx.x] = v[j];
        __syncthreads();
        for (int off = 128; off >= 1; off >>= 1) {
            if (threadIdx.x < off) red[threadIdx.x] += red[threadIdx.x + off];
            __syncthreads();
        }
        if (threadIdx.x == 0) atomicAdd(&stats[j], red[0]);
        __syncthreads();
    }
}

// ---------------- K6: pos BN affine (a1, a0) per 64 channels ----------------
__global__ void pos_bn_kernel(const float* __restrict__ stats, const float* __restrict__ pw1,
                              const float* __restrict__ pb1, const float* __restrict__ pg1,
                              const float* __restrict__ pbe1, float* __restrict__ posA) {
    int c = threadIdx.x;
    if (c >= PHH) return;
    float M = (float)(BB * NN * KK);
    float mu0 = stats[0] / M, mu1 = stats[1] / M, mu2 = stats[2] / M;
    float E00 = stats[3] / M, E11 = stats[4] / M, E22 = stats[5] / M;
    float E01 = stats[6] / M, E02 = stats[7] / M, E12 = stats[8] / M;
    float w0 = pw1[c * 3], w1 = pw1[c * 3 + 1], w2 = pw1[c * 3 + 2];
    float wmu = w0 * mu0 + w1 * mu1 + w2 * mu2;
    float mean_h = wmu + pb1[c];
    float Eh2 = w0 * w0 * E00 + w1 * w1 * E11 + w2 * w2 * E22
              + 2.f * (w0 * w1 * E01 + w0 * w2 * E02 + w1 * w2 * E12)
              + 2.f * pb1[c] * wmu + pb1[c] * pb1[c];
    float var = Eh2 - mean_h * mean_h;
    float a1 = pg1[c] * rsqrtf(var + EPSF);
    posA[c] = a1;
    posA[PHH + c] = pbe1[c] - mean_h * a1;
}

// ---------------- K7a: P1 = relu(BNaffine(pw1 . pos_rel)) bf16 (M x 64) ----------------
__global__ __launch_bounds__(256) void p1_kernel(const float* __restrict__ pos,
                                                 const int* __restrict__ idx,
                                                 const float* __restrict__ pw1,
                                                 const float* __restrict__ pb1,
                                                 const float* __restrict__ posA,
                                                 ushort_t* __restrict__ p1) {
    int gid = blockIdx.x * 256 + threadIdx.x;
    int samp = gid >> 6, c = gid & 63;
    int p = samp >> 4;
    int b = p >> 12, n = p & (NN - 1);
    int m = idx[samp];
    const float* px = pos + (size_t)b * 3 * NN;
    float dx = px[n] - px[m];
    float dy = px[NN + n] - px[NN + m];
    float dz = px[2 * NN + n] - px[2 * NN + m];
    float h = pw1[c * 3] * dx + pw1[c * 3 + 1] * dy + pw1[c * 3 + 2] * dz + pb1[c];
    p1[gid] = f2b(fmaxf(h * posA[c] + posA[PHH + c], 0.f));
}

// ---------------- K8: mu = column sums of s (coalesced full-row reads) ----------------
__global__ __launch_bounds__(256) void mu_kernel(const ushort_t* __restrict__ sb16,
                                                 float* __restrict__ mu) {
    __shared__ float red[8][DIMD];
    int t = threadIdx.x;
    int rg = t >> 5;          // row group 0..7 (64 rows each)
    int c0 = (t & 31) * 8;    // 8 channels per lane; 32 lanes cover a full 256-ch row
    const ushort_t* p = sb16 + ((size_t)blockIdx.x * 512 + rg * 64) * DIMD + c0;
    float a0 = 0.f, a1 = 0.f, a2 = 0.f, a3 = 0.f, a4 = 0.f, a5 = 0.f, a6 = 0.f, a7 = 0.f;
    for (int i = 0; i < 64; ++i) {
        u16x8 v = *(const u16x8*)(p + (size_t)i * DIMD);
        a0 += b2f(v[0]); a1 += b2f(v[1]); a2 += b2f(v[2]); a3 += b2f(v[3]);
        a4 += b2f(v[4]); a5 += b2f(v[5]); a6 += b2f(v[6]); a7 += b2f(v[7]);
    }
    red[rg][c0] = a0; red[rg][c0 + 1] = a1; red[rg][c0 + 2] = a2; red[rg][c0 + 3] = a3;
    red[rg][c0 + 4] = a4; red[rg][c0 + 5] = a5; red[rg][c0 + 6] = a6; red[rg][c0 + 7] = a7;
    __syncthreads();
    float s = 0.f;
#pragma unroll
    for (int g = 0; g < 8; ++g) s += red[g][t];
    atomicAdd(&mu[t], s);
}

// ---------------- K9: R partials via MFMA ----------------
__global__ __launch_bounds__(256) void rg_kernel(const ushort_t* __restrict__ S,
                                                 float* __restrict__ Rpart) {
    __shared__ ushort_t ls[32 * LSTR];
    int t = threadIdx.x;
    int lane = t & 63, w = t >> 6;
    int wr = w >> 1, wc = w & 1;
    int ti = blockIdx.y >> 1, tj = blockIdx.y & 1;
    int m16 = lane & 15, kg = lane >> 4;
    size_t kbase = (size_t)blockIdx.x * RKCH;

    f32x4 acc[4][4];
#pragma unroll
    for (int i = 0; i < 4; ++i)
#pragma unroll
        for (int j = 0; j < 4; ++j) acc[i][j] = (f32x4){0.f, 0.f, 0.f, 0.f};

    int lm = t >> 3;
    int lc = (t & 7) * 32;
    const ushort_t* gS = S + (kbase + lm) * DIMD + lc;
    ushort_t* lp = ls + lm * LSTR + lc;

    for (int kt = 0; kt < RKCH / 32; ++kt) {
        const ushort_t* gp = gS + (size_t)kt * 32 * DIMD;
        u16x8 v0 = *(const u16x8*)(gp);
        u16x8 v1 = *(const u16x8*)(gp + 8);
        u16x8 v2 = *(const u16x8*)(gp + 16);
        u16x8 v3 = *(const u16x8*)(gp + 24);
        __syncthreads();
#pragma unroll
        for (int q = 0; q < 4; ++q) {
            *(u16x2*)(lp + 0 + 2 * q) = (u16x2){v0[2 * q], v0[2 * q + 1]};
            *(u16x2*)(lp + 8 + 2 * q) = (u16x2){v1[2 * q], v1[2 * q + 1]};
            *(u16x2*)(lp + 16 + 2 * q) = (u16x2){v2[2 * q], v2[2 * q + 1]};
            *(u16x2*)(lp + 24 + 2 * q) = (u16x2){v3[2 * q], v3[2 * q + 1]};
        }
        __syncthreads();
        short8 af[4], bf[4];
#pragma unroll
        for (int i = 0; i < 4; ++i) {
            int chA = ti * 128 + wr * 64 + i * 16 + m16;
            int chB = tj * 128 + wc * 64 + i * 16 + m16;
#pragma unroll
            for (int j = 0; j < 8; ++j) {
                int k = kg * 8 + j;
                af[i][j] = (short)ls[k * LSTR + chA];
                bf[i][j] = (short)ls[k * LSTR + chB];
            }
        }
#pragma unroll
        for (int i = 0; i < 4; ++i)
#pragma unroll
            for (int j = 0; j < 4; ++j)
                acc[i][j] = __builtin_amdgcn_mfma_f32_16x16x32_bf16(af[i], bf[j], acc[i][j], 0, 0, 0);
    }

    float* rp = Rpart + (size_t)blockIdx.x * (DIMD * DIMD);
#pragma unroll
    for (int i = 0; i < 4; ++i) {
        int r0 = ti * 128 + wr * 64 + i * 16 + kg * 4;
#pragma unroll
        for (int j = 0; j < 4; ++j) {
            int cn = tj * 128 + wc * 64 + j * 16 + m16;
#pragma unroll
            for (int rg = 0; rg < 4; ++rg)
                rp[(size_t)(r0 + rg) * DIMD + cn] = acc[i][j][rg];
        }
    }
}

// ---------------- K9b: reduce R partials ----------------
__global__ __launch_bounds__(256) void r_reduce_kernel(const float* __restrict__ Rpart,
                                                       float* __restrict__ R) {
    int e = blockIdx.x * 256 + threadIdx.x;
    float s = 0.f;
    for (int p = 0; p < RSPLIT; ++p) s += Rpart[(size_t)p * (DIMD * DIMD) + e];
    R[e] = s;
}

// ---------------- K10: attn BN -> fused scale/offset per hidden channel ----------------
__global__ __launch_bounds__(256) void attn_bn_kernel(const float* __restrict__ R,
                                                      const float* __restrict__ mu,
                                                      const float* __restrict__ aw1,
                                                      const float* __restrict__ ab1,
                                                      const float* __restrict__ ag1,
                                                      const float* __restrict__ abe1,
                                                      float* __restrict__ attA) {
    int c = blockIdx.x;
    int t = threadIdx.x;
    __shared__ float wsh[DIMD];
    __shared__ float red[DIMD];
    wsh[t] = aw1[(size_t)c * DIMD + t];
    __syncthreads();
    const float* Rr = R + (size_t)t * DIMD;
    float q = 0.f;
#pragma unroll 4
    for (int j = 0; j < DIMD; ++j) q += Rr[j] * wsh[j];
    red[t] = q * wsh[t];
    __syncthreads();
    for (int off = 128; off >= 1; off >>= 1) {
        if (t < off) red[t] += red[t + off];
        __syncthreads();
    }
    float wRw = red[0];
    __syncthreads();
    red[t] = wsh[t] * mu[t];
    __syncthreads();
    for (int off = 128; off >= 1; off >>= 1) {
        if (t < off) red[t] += red[t + off];
        __syncthreads();
    }
    if (t == 0) {
        float M = (float)(BB * NN * KK);
        float wmu = red[0] / M;
        float b1c = ab1[c];
        float Eh = wmu + b1c;
        float Eh2 = wRw / M + 2.f * b1c * wmu + b1c * b1c;
        float var = Eh2 - Eh * Eh;
        float a1 = ag1[c] * rsqrtf(var + EPSF);
        attA[c] = a1;
        attA[AHH + c] = a1 * b1c + abe1[c] - Eh * a1;
    }
}

// ---------------- K10b: convert all weights to bf16 (+ W2 to fp8 x64) ----------------
__global__ void cvt_w_kernel(const float* __restrict__ aw1, const float* __restrict__ aw2,
                             const float* __restrict__ pw2,
                             const float* __restrict__ mw1, const float* __restrict__ mws,
                             const float* __restrict__ mw2,
                             const float* __restrict__ wk, const float* __restrict__ wq,
                             const float* __restrict__ wv,
                             ushort_t* __restrict__ w1b, ushort_t* __restrict__ w2b,
                             ushort_t* __restrict__ pw2b,
                             ushort_t* __restrict__ w1vb, ushort_t* __restrict__ wsvb,
                             ushort_t* __restrict__ w2vb,
                             ushort_t* __restrict__ wkb, ushort_t* __restrict__ wqb,
                             ushort_t* __restrict__ wvb,
                             uchar_t* __restrict__ w2f8) {
    int i = blockIdx.x * 256 + threadIdx.x;
    int o = i;
    if (o < 262144) { w1b[o] = f2b(aw1[o]); return; }   o -= 262144;
    if (o < 262144) { w2b[o] = f2b(aw2[o]); w2f8[o] = f2f8(aw2[o] * 64.f); return; } o -= 262144;
    if (o < 16384)  { pw2b[o] = f2b(pw2[o]); return; }  o -= 16384;
    if (o < 32768)  { w1vb[o] = f2b(mw1[o]); return; }  o -= 32768;
    if (o < 32768)  { wsvb[o] = f2b(mws[o]); return; }  o -= 32768;
    if (o < 16384)  { w2vb[o] = f2b(mw2[o]); return; }  o -= 16384;
    if (o < 32768)  { wkb[o] = f2b(wk[o]); return; }    o -= 32768;
    if (o < 32768)  { wqb[o] = f2b(wq[o]); return; }    o -= 32768;
    if (o < 32768)  { wvb[o] = f2b(wv[o]); }
}

// ---------------- MFMA GEMM (s-build): s = q - k_g + (P1·pw2^T + pb2) ----------------
template <int KDIM>
__global__ __launch_bounds__(256) void gemmS_kernel(const ushort_t* __restrict__ A,
                                                    const ushort_t* __restrict__ Bm,
                                                    const float* __restrict__ p0,
                                                    ushort_t* __restrict__ Sb,
                                                    const float* __restrict__ qT,
                                                    const float* __restrict__ kT,
                                                    const int* __restrict__ gidx) {
    __shared__ ushort_t lA[128 * 32];
    __shared__ ushort_t lB[128 * 32];
    int t = threadIdx.x;
    int lane = t & 63, w = t >> 6;
    int wr = w >> 1, wc = w & 1;
    size_t row0 = (size_t)blockIdx.x * 128;
    int col0 = blockIdx.y * 128;
    int m16 = lane & 15, kg = lane >> 4;

    f32x4 acc[4][4];
#pragma unroll
    for (int i = 0; i < 4; ++i)
#pragma unroll
        for (int j = 0; j < 4; ++j) acc[i][j] = (f32x4){0.f, 0.f, 0.f, 0.f};

    const ushort_t* gA = A + (row0 + (size_t)w * 16 + m16) * KDIM + kg * 8;
    const ushort_t* gB = Bm + ((size_t)(col0 + w * 16 + m16)) * KDIM + kg * 8;
    ushort_t* lA0 = lA + w * 512;
    ushort_t* lB0 = lB + w * 512;

    for (int kt = 0; kt < KDIM / 32; ++kt) {
        int ko = kt * 32;
        GLDS16(gA + ko, lA0);
        GLDS16(gA + (size_t)64 * KDIM + ko, lA0 + 2048);
        GLDS16(gB + ko, lB0);
        GLDS16(gB + (size_t)64 * KDIM + ko, lB0 + 2048);
        __syncthreads();
        short8 af[4], bf[4];
#pragma unroll
        for (int i = 0; i < 4; ++i) {
            af[i] = *(const short8*)(lA + ((wr * 4 + i) * 512 + kg * 128 + m16 * 8));
            bf[i] = *(const short8*)(lB + ((wc * 4 + i) * 512 + kg * 128 + m16 * 8));
        }
#pragma unroll
        for (int i = 0; i < 4; ++i)
#pragma unroll
            for (int j = 0; j < 4; ++j)
                acc[i][j] = __builtin_amdgcn_mfma_f32_16x16x32_bf16(af[i], bf[j], acc[i][j], 0, 0, 0);
        __syncthreads();
    }

    int nn[4]; float bi[4];
#pragma unroll
    for (int j = 0; j < 4; ++j) { nn[j] = col0 + wc * 64 + j * 16 + m16; bi[j] = p0[nn[j]]; }
#pragma unroll
    for (int i = 0; i < 4; ++i) {
        size_t r = row0 + wr * 64 + i * 16 + kg * 4;
#pragma unroll
        for (int rg = 0; rg < 4; ++rg) {
            size_t rr = r + rg;
            int p = (int)(rr >> 4);
            int krow = (p & ~(NN - 1)) + gidx[rr];
            const float* qrow = qT + (size_t)p * DIMD;
            const float* kro = kT + (size_t)krow * DIMD;
#pragma unroll
            for (int j = 0; j < 4; ++j) {
                float sv = qrow[nn[j]] - kro[nn[j]] + acc[i][j][rg] + bi[j];
                Sb[rr * (size_t)DIMD + nn[j]] = f2b(sv);
            }
        }
    }
}

// ---------------- K11: fused attn MLP + softmax + aggregation (v5, reverted) --------
// 40 KB LDS: lS 32K bf16 (staged once — the LDS staging IS the reuse mechanism;
// R13's no-lS variant re-read S 8x from HBM: FETCH 125->970 MB) + lHt 8K fp8.
// GEMM2 in fp8 (W2 scaled x64, un-scaled 1/64 in epilogue). (256,3): no spill.
__global__ __launch_bounds__(256, 3) void fused_mlp_kernel(const ushort_t* __restrict__ S,
                                                        const ushort_t* __restrict__ w1b,
                                                        const uchar_t* __restrict__ w2f8,
                                                        const float* __restrict__ attA,
                                                        const float* __restrict__ ab2,
                                                        const int* __restrict__ idx,
                                                        const float* __restrict__ qT,
                                                        const float* __restrict__ kT,
                                                        const float* __restrict__ vT,
                                                        float* __restrict__ aggT) {
    __shared__ char smem[40960];
    ushort_t* lS  = (ushort_t*)smem;             // 32 KB: 64 smp x 256 k bf16
    uchar_t*  lHt = (uchar_t*)(smem + 32768);    // 8 KB: 128 hid x 64 smp fp8, frag layout
    ushort_t* lgB = (ushort_t*)smem;             // epilogue: 256 out x 64 smp bf16, stride 72

    int t = threadIdx.x;
    int lane = t & 63, w = t >> 6;
    int m16 = lane & 15, kg = lane >> 4;
    size_t row0 = (size_t)blockIdx.x * 64;

#pragma unroll
    for (int i = 0; i < 8; ++i) {
        int lb = w * 8 + i;
        int kt = lb >> 2, st = lb & 3;
        const ushort_t* gp = S + (row0 + st * 16 + m16) * DIMD + kt * 32 + kg * 8;
        GLDS16(gp, lS + lb * 512);
    }

    f32x4 acc2[4][4];
#pragma unroll
    for (int i = 0; i < 4; ++i)
#pragma unroll
        for (int j = 0; j < 4; ++j) acc2[i][j] = (f32x4){0.f, 0.f, 0.f, 0.f};

    __syncthreads();

    for (int jc = 0; jc < 8; ++jc) {
        f32x4 acc1[2][4];
#pragma unroll
        for (int hi = 0; hi < 2; ++hi)
#pragma unroll
            for (int sj = 0; sj < 4; ++sj) acc1[hi][sj] = (f32x4){0.f, 0.f, 0.f, 0.f};
#pragma unroll
        for (int kt = 0; kt < 8; ++kt) {
            short8 af[2], bf[4];
#pragma unroll
            for (int hi = 0; hi < 2; ++hi)
                af[hi] = *(const short8*)(w1b + ((size_t)(jc * 128 + w * 32 + hi * 16 + m16)) * DIMD + kt * 32 + kg * 8);
#pragma unroll
            for (int sj = 0; sj < 4; ++sj)
                bf[sj] = *(const short8*)(lS + (kt * 4 + sj) * 512 + kg * 128 + m16 * 8);
#pragma unroll
            for (int hi = 0; hi < 2; ++hi)
#pragma unroll
                for (int sj = 0; sj < 4; ++sj)
                    acc1[hi][sj] = __builtin_amdgcn_mfma_f32_16x16x32_bf16(af[hi], bf[sj], acc1[hi][sj], 0, 0, 0);
        }
        __syncthreads();   // prior GEMM2 reads of lHt complete
#pragma unroll
        for (int hi = 0; hi < 2; ++hi) {
            float4 sc4 = *(const float4*)(attA + jc * 128 + w * 32 + hi * 16 + kg * 4);
            float4 of4 = *(const float4*)(attA + AHH + jc * 128 + w * 32 + hi * 16 + kg * 4);
#pragma unroll
            for (int sj = 0; sj < 4; ++sj) {
                float h0 = fmaxf(sc4.x * acc1[hi][sj][0] + of4.x, 0.f);
                float h1 = fmaxf(sc4.y * acc1[hi][sj][1] + of4.y, 0.f);
                float h2 = fmaxf(sc4.z * acc1[hi][sj][2] + of4.z, 0.f);
                float h3 = fmaxf(sc4.w * acc1[hi][sj][3] + of4.w, 0.f);
                int p01 = __builtin_amdgcn_cvt_pk_fp8_f32(h0, h1, 0, false);
                int pk = __builtin_amdgcn_cvt_pk_fp8_f32(h2, h3, p01, true);
                int ah = (w * 4 + sj) * 512 + (hi * 2 + (kg >> 1)) * 128 + m16 * 8 + (kg & 1) * 4;
                *(int*)(lHt + ah) = pk;
            }
        }
        __syncthreads();
#pragma unroll
        for (int g = 0; g < 4; ++g) {
            i64 af2[4], bf2[4];
#pragma unroll
            for (int oi = 0; oi < 4; ++oi)
                af2[oi] = *(const i64*)(w2f8 + ((size_t)(w * 64 + oi * 16 + m16)) * AHH + jc * 128 + g * 32 + kg * 8);
#pragma unroll
            for (int sj = 0; sj < 4; ++sj)
                bf2[sj] = *(const i64*)(lHt + (g * 4 + sj) * 512 + kg * 128 + m16 * 8);
#pragma unroll
            for (int oi = 0; oi < 4; ++oi)
#pragma unroll
                for (int sj = 0; sj < 4; ++sj)
                    acc2[oi][sj] = __builtin_amdgcn_mfma_f32_16x16x32_fp8_fp8(af2[oi], bf2[sj], acc2[oi][sj], 0, 0, 0);
        }
    }
    __syncthreads();

    // phase 1: logits (acc2/64 + b2) -> lgB[out][smp] (bf16, stride 72)
    const float invsc = 0.015625f;
#pragma unroll
    for (int oi = 0; oi < 4; ++oi) {
        int ob = w * 64 + oi * 16 + kg * 4;
        float4 b2v = *(const float4*)(ab2 + ob);
#pragma unroll
        for (int sj = 0; sj < 4; ++sj) {
            int smp = sj * 16 + m16;
            lgB[(ob + 0) * 72 + smp] = f2b(acc2[oi][sj][0] * invsc + b2v.x);
            lgB[(ob + 1) * 72 + smp] = f2b(acc2[oi][sj][1] * invsc + b2v.y);
            lgB[(ob + 2) * 72 + smp] = f2b(acc2[oi][sj][2] * invsc + b2v.z);
            lgB[(ob + 3) * 72 + smp] = f2b(acc2[oi][sj][3] * invsc + b2v.w);
        }
    }
    __syncthreads();

    // phase 2: thread t owns out-channel t; 4 points; serial softmax in regs.
    int out = t;
    for (int pt = 0; pt < 4; ++pt) {
        int pid = (int)(row0 >> 4) + pt;
        u16x8 v0 = *(const u16x8*)(lgB + out * 72 + pt * 16);
        u16x8 v1 = *(const u16x8*)(lgB + out * 72 + pt * 16 + 8);
        float lg[KK];
#pragma unroll
        for (int s = 0; s < 8; ++s) { lg[s] = b2f(v0[s]); lg[s + 8] = b2f(v1[s]); }
        float mx = lg[0];
#pragma unroll
        for (int s = 1; s < KK; ++s) mx = fmaxf(mx, lg[s]);
        float se = 0.f;
#pragma unroll
        for (int s = 0; s < KK; ++s) { lg[s] = expf(lg[s] - mx); se += lg[s]; }
        float inv = 1.f / se;
        int base = pid & ~(NN - 1);
        float acc = 0.f;
#pragma unroll
        for (int s = 0; s < KK; ++s) {
            int row = pid * KK + s;
            int krow = base + idx[row];
            float sv = b2f(S[(size_t)row * DIMD + out]);
            float kv = kT[(size_t)krow * DIMD + out];
            acc += lg[s] * (sv + kv);
        }
        float vf = vT[(size_t)pid * DIMD + out];
        float q  = qT[(size_t)pid * DIMD + out];
        aggT[(size_t)pid * DIMD + out] = vf - q + acc * inv;
    }
}

// ---------------- K12: y = we·agg + be + value (both LDS-staged, coalesced) --------
__global__ __launch_bounds__(256) void final_kernel(const float* __restrict__ aggT,
                                                    const float* __restrict__ we,
                                                    const float* __restrict__ be,
                                                    const float* __restrict__ valueTf,
                                                    float* __restrict__ out) {
    __shared__ float xs[2 * FPT][DIMD];
    __shared__ float vs[2 * FPT][CC];
    int b = blockIdx.y;
    int n0 = blockIdx.x * (2 * FPT);
    int t = threadIdx.x;
    const float4* src = (const float4*)(aggT + ((size_t)b * NN + n0) * DIMD);
    float4* dst = (float4*)xs;
#pragma unroll
    for (int l = 0; l < (2 * FPT * DIMD / 4) / 256; ++l) dst[t + 256 * l] = src[t + 256 * l];
    const float4* src2 = (const float4*)(valueTf + ((size_t)b * NN + n0) * CC);
    float4* dst2 = (float4*)vs;
#pragma unroll
    for (int l = 0; l < (2 * FPT * CC / 4) / 256; ++l) dst2[t + 256 * l] = src2[t + 256 * l];
    __syncthreads();
    int o = t & 127, ph = t >> 7;
    float acc[FPT];
#pragma unroll
    for (int p = 0; p < FPT; ++p) acc[p] = 0.f;
    const float4* wr = (const float4*)(we + (size_t)o * DIMD);
#pragma unroll 8
    for (int i4 = 0; i4 < DIMD / 4; ++i4) {
        float4 w4 = wr[i4];
#pragma unroll
        for (int p = 0; p < FPT; ++p) {
            float4 x4 = *(const float4*)&xs[ph * FPT + p][i4 * 4];
            acc[p] += w4.x * x4.x + w4.y * x4.y + w4.z * x4.z + w4.w * x4.w;
        }
    }
    float bo = be[o];
#pragma unroll
    for (int p = 0; p < FPT; ++p) {
        size_t oi = ((size_t)b * CC + o) * NN + n0 + ph * FPT + p;
        out[oi] = acc[p] + bo + vs[ph * FPT + p][o];
    }
}

extern "C" void kernel_launch(void* const* d_in, const int* in_sizes, int n_in,
                              void* d_out, int out_size, void* d_ws, size_t ws_size,
                              hipStream_t stream) {
    (void)in_sizes; (void)n_in; (void)out_size; (void)ws_size;
    const float* pos     = (const float*)d_in[0];
    const float* key     = (const float*)d_in[1];
    const float* query   = (const float*)d_in[2];
    const float* mlpv_w1 = (const float*)d_in[3];
    const float* mlpv_b1 = (const float*)d_in[4];
    const float* mlpv_w2 = (const float*)d_in[5];
    const float* mlpv_b2 = (const float*)d_in[6];
    const float* mlpv_ws = (const float*)d_in[7];
    const float* mlpv_bs = (const float*)d_in[8];
    const float* wk  = (const float*)d_in[9];
    const float* bk  = (const float*)d_in[10];
    const float* wq  = (const float*)d_in[11];
    const float* bq  = (const float*)d_in[12];
    const float* wv  = (const float*)d_in[13];
    const float* bv  = (const float*)d_in[14];
    const float* pw1 = (const float*)d_in[15];
    const float* pb1 = (const float*)d_in[16];
    const float* pg1 = (const float*)d_in[17];
    const float* pbe1= (const float*)d_in[18];
    const float* pw2 = (const float*)d_in[19];
    const float* pb2 = (const float*)d_in[20];
    const float* aw1 = (const float*)d_in[21];
    const float* ab1 = (const float*)d_in[22];
    const float* ag1 = (const float*)d_in[23];
    const float* abe1= (const float*)d_in[24];
    const float* aw2 = (const float*)d_in[25];
    const float* ab2 = (const float*)d_in[26];
    const float* we  = (const float*)d_in[27];
    const float* be  = (const float*)d_in[28];
    float* out = (float*)d_out;

    char* wsb = (char*)d_ws;
    size_t off = 0;
    auto alloc = [&](size_t bytes) {
        void* p = wsb + off;
        off += (bytes + 255) & ~(size_t)255;
        return p;
    };
    const size_t M = (size_t)BB * NN * KK;   // 131072 rows
    const size_t P = (size_t)BB * NN;        // 8192 points
    int*   idx   = (int*)  alloc(M * 4);
    ushort_t* kqT     = (ushort_t*)alloc(P * 256 * 2);
    ushort_t* h1T     = (ushort_t*)alloc(P * CC * 2);
    float*    valueTf = (float*)   alloc(P * CC * 4);
    ushort_t* valueTb = (ushort_t*)alloc(P * CC * 2);
    float* kT    = (float*)alloc(P * DIMD * 4);
    float* qT    = (float*)alloc(P * DIMD * 4);
    float* vT    = (float*)alloc(P * DIMD * 4);
    float* aggT  = (float*)alloc(P * DIMD * 4);
    float* zero0 = (float*)alloc((size_t)(16 + 256 + 65536) * 4);
    float* stats = zero0;
    float* mu    = zero0 + 16;
    float* R     = zero0 + 16 + 256;
    float* posA  = (float*)alloc((size_t)2 * PHH * 4);
    float* attA  = (float*)alloc((size_t)2 * AHH * 4);
    ushort_t* w1b  = (ushort_t*)alloc((size_t)AHH * DIMD * 2);
    ushort_t* w2b  = (ushort_t*)alloc((size_t)DIMD * AHH * 2);
    uchar_t*  w2f8 = (uchar_t*) alloc((size_t)DIMD * AHH);
    ushort_t* pw2b = (ushort_t*)alloc((size_t)DIMD * PHH * 2);
    ushort_t* w1vb = (ushort_t*)alloc((size_t)CC * 256 * 2);
    ushort_t* wsvb = (ushort_t*)alloc((size_t)CC * 256 * 2);
    ushort_t* w2vb = (ushort_t*)alloc((size_t)CC * CC * 2);
    ushort_t* wkb  = (ushort_t*)alloc((size_t)DIMD * CC * 2);
    ushort_t* wqb  = (ushort_t*)alloc((size_t)DIMD * CC * 2);
    ushort_t* wvb  = (ushort_t*)alloc((size_t)DIMD * CC * 2);
    ushort_t* sb16 = (ushort_t*)alloc(M * DIMD * 2);          //  67 MB
    char* ovl = (char*)alloc((size_t)RSPLIT * DIMD * DIMD * 4);
    ushort_t* p1buf = (ushort_t*)ovl;
    float*    Rpart = (float*)ovl;

    int ZN = 16 + 256 + 65536;
    zero_kernel<<<(ZN + 255) / 256, 256, 0, stream>>>(zero0, ZN);
    knn_kernel<<<BB * NN, 256, 0, stream>>>(pos, idx);
    cvt_w_kernel<<<(720896 + 255) / 256, 256, 0, stream>>>(aw1, aw2, pw2, mlpv_w1, mlpv_ws, mlpv_w2,
                                                           wk, wq, wv, w1b, w2b, pw2b,
                                                           w1vb, wsvb, w2vb, wkb, wqb, wvb, w2f8);
    cvtx_kernel<<<dim3(NN / 64, BB), 256, 0, stream>>>(key, query, kqT);
    gemmT_kernel<256, 256, 0, 128><<<dim3(P / 128, 1), 256, 0, stream>>>(kqT, w1vb, mlpv_b1, nullptr, h1T);
    gemmval_kernel<<<dim3(P / 128, 1), 256, 0, stream>>>(kqT, h1T, wsvb, w2vb, mlpv_b2, mlpv_bs, valueTf, valueTb);
    gemmkq_kernel<<<dim3(P / 128, 4), 256, 0, stream>>>(kqT, wkb, wqb, bk, bq, kT, qT);
    gemmT_kernel<128, 128, 1, 256><<<dim3(P / 128, 2), 256, 0, stream>>>(valueTb, wvb, bv, vT, nullptr);
    pos_stats_kernel<<<BB * NN * KK / 256, 256, 0, stream>>>(pos, idx, stats);
    pos_bn_kernel<<<1, 64, 0, stream>>>(stats, pw1, pb1, pg1, pbe1, posA);
    p1_kernel<<<(int)(M * PHH / 256), 256, 0, stream>>>(pos, idx, pw1, pb1, posA, p1buf);
    gemmS_kernel<PHH><<<dim3(M / 128, DIMD / 128), 256, 0, stream>>>(p1buf, pw2b, pb2, sb16, qT, kT, idx);
    mu_kernel<<<(int)(M / 512), 256, 0, stream>>>(sb16, mu);
    rg_kernel<<<dim3(RSPLIT, 4), 256, 0, stream>>>(sb16, Rpart);
    r_reduce_kernel<<<DIMD * DIMD / 256, 256, 0, stream>>>(Rpart, R);
    attn_bn_kernel<<<AHH, DIMD, 0, stream>>>(R, mu, aw1, ab1, ag1, abe1, attA);
    fused_mlp_kernel<<<(int)(M / 64), 256, 0, stream>>>(sb16, w1b, w2f8, attA, ab2, idx, qT, kT, vT, aggT);
    final_kernel<<<dim3(NN / (2 * FPT), BB), 256, 0, stream>>>(aggT, we, be, valueTf, out);
}